// Round 9
// baseline (472.105 us; speedup 1.0000x reference)
//
#include <hip/hip_runtime.h>
#include <stdint.h>

#define NN 8192
#define FIN 512
#define FOUT 256
#define ALPHA 0.2f
#define KSPLIT 8
#define ITILE 128

typedef float f32x4 __attribute__((ext_vector_type(4)));
typedef short s16x8 __attribute__((ext_vector_type(8)));

__device__ __forceinline__ uint16_t f2bf(float f) {
  union { float f; uint32_t u; } v; v.f = f;
  uint32_t u = v.u + 0x7fffu + ((v.u >> 16) & 1u);
  return (uint16_t)(u >> 16);
}

// ---------------- 1. merged: wt[f][k] = bf16(W[k][f])  +  wa1/wa2 = W @ a1/a2 ----------------
__global__ __launch_bounds__(256) void k_wa_prep(const float* __restrict__ W,
                                                 const float* __restrict__ a,
                                                 uint16_t* __restrict__ wt,
                                                 float* __restrict__ wa1, float* __restrict__ wa2) {
  int bx = blockIdx.x;
  int tid = threadIdx.x;
  if (bx < 128) {
    int idx = bx * 256 + tid;
    int f  = idx >> 7;
    int k4 = (idx & 127) * 4;
    ushort4 o;
    o.x = f2bf(W[(size_t)(k4 + 0) * FOUT + f]);
    o.y = f2bf(W[(size_t)(k4 + 1) * FOUT + f]);
    o.z = f2bf(W[(size_t)(k4 + 2) * FOUT + f]);
    o.w = f2bf(W[(size_t)(k4 + 3) * FOUT + f]);
    *(ushort4*)(wt + (size_t)f * FIN + k4) = o;
  } else {
    __shared__ float a1[256], a2[256];
    a1[tid] = a[tid];
    a2[tid] = a[tid + 256];
    __syncthreads();
    int m = (bx - 128) * 256 + tid;   // 0..511
    const float* wrow = W + (size_t)m * FOUT;
    float s1 = 0.f, s2 = 0.f;
    for (int k = 0; k < FOUT; k += 4) {
      f32x4 v = *(const f32x4*)(wrow + k);
#pragma unroll
      for (int i = 0; i < 4; i++) {
        s1 += v[i] * a1[k + i];
        s2 += v[i] * a2[k + i];
      }
    }
    wa1[m] = s1; wa2[m] = s2;
  }
}

// ---------------- 2. f1/f2 = x @ wa1/wa2 + x->bf16 + l_arr zero ----------------
__global__ __launch_bounds__(256) void k_f1f2(const float* __restrict__ x,
                                              const float* __restrict__ wa1,
                                              const float* __restrict__ wa2,
                                              float* __restrict__ f1, float* __restrict__ f2,
                                              uint16_t* __restrict__ xb,
                                              float* __restrict__ l_arr) {
  __shared__ float s1[512], s2[512];
  int tid = threadIdx.x;
  if (tid < 4) l_arr[blockIdx.x * 4 + tid] = 0.f;
  s1[tid] = wa1[tid]; s1[tid + 256] = wa1[tid + 256];
  s2[tid] = wa2[tid]; s2[tid + 256] = wa2[tid + 256];
  __syncthreads();
  int w = tid >> 6, l = tid & 63;
  int row = blockIdx.x * 4 + w;
  const float* xr = x + (size_t)row * FIN + l * 8;
  f32x4 v0 = *(const f32x4*)xr;
  f32x4 v1 = *(const f32x4*)(xr + 4);
  uint4 pk;
  pk.x = (uint32_t)f2bf(v0[0]) | ((uint32_t)f2bf(v0[1]) << 16);
  pk.y = (uint32_t)f2bf(v0[2]) | ((uint32_t)f2bf(v0[3]) << 16);
  pk.z = (uint32_t)f2bf(v1[0]) | ((uint32_t)f2bf(v1[1]) << 16);
  pk.w = (uint32_t)f2bf(v1[2]) | ((uint32_t)f2bf(v1[3]) << 16);
  *(uint4*)(xb + (size_t)row * FIN + l * 8) = pk;
  int kb = l * 8;
  float d1 = 0.f, d2 = 0.f;
#pragma unroll
  for (int i = 0; i < 4; i++) {
    d1 += v0[i] * s1[kb + i] + v1[i] * s1[kb + 4 + i];
    d2 += v0[i] * s2[kb + i] + v1[i] * s2[kb + 4 + i];
  }
#pragma unroll
  for (int off = 32; off; off >>= 1) {
    d1 += __shfl_down(d1, off);
    d2 += __shfl_down(d2, off);
  }
  if (l == 0) { f1[row] = d1; f2[row] = d2; }
}

// ---------------- 3. ht[f][i] = (xb @ W)^T  -- gemm + LDS-transpose epilogue ----------------
__global__ __launch_bounds__(256, 2) void k_gemm_ht(const uint16_t* __restrict__ xb,
                                                    const uint16_t* __restrict__ wt,
                                                    uint16_t* __restrict__ ht) {
  __shared__ uint16_t Xs[64][72];
  __shared__ uint16_t Ws[64][72];
  __shared__ uint16_t T[64][72];
  int i0 = blockIdx.x * 64;
  int f0 = blockIdx.y * 64;
  int tid = threadIdx.x;
  int w = tid >> 6, l = tid & 63;
  int q = l >> 4, r16 = l & 15;
  f32x4 acc[4];
#pragma unroll
  for (int b = 0; b < 4; b++) acc[b] = (f32x4)0.f;

  int srow = tid >> 2, sch = tid & 3;
  for (int k0 = 0; k0 < FIN; k0 += 64) {
    const uint16_t* xp = xb + (size_t)(i0 + srow) * FIN + k0;
    const uint16_t* wp = wt + (size_t)(f0 + srow) * FIN + k0;
    uint4 xv0 = *(const uint4*)(xp + sch * 8);
    uint4 xv1 = *(const uint4*)(xp + 32 + sch * 8);
    uint4 wv0 = *(const uint4*)(wp + sch * 8);
    uint4 wv1 = *(const uint4*)(wp + 32 + sch * 8);
    *(uint4*)(&Xs[srow][sch * 8]) = xv0;
    *(uint4*)(&Xs[srow][32 + sch * 8]) = xv1;
    *(uint4*)(&Ws[srow][sch * 8]) = wv0;
    *(uint4*)(&Ws[srow][32 + sch * 8]) = wv1;
    __syncthreads();
#pragma unroll
    for (int c = 0; c < 2; c++) {
      s16x8 A = *(const s16x8*)(&Xs[w * 16 + r16][c * 32 + q * 8]);
      s16x8 B[4];
#pragma unroll
      for (int b = 0; b < 4; b++) B[b] = *(const s16x8*)(&Ws[b * 16 + r16][c * 32 + q * 8]);
#pragma unroll
      for (int b = 0; b < 4; b++)
        acc[b] = __builtin_amdgcn_mfma_f32_16x16x32_bf16(A, B[b], acc[b], 0, 0, 0);
    }
    __syncthreads();
  }
#pragma unroll
  for (int b = 0; b < 4; b++)
#pragma unroll
    for (int reg = 0; reg < 4; reg++)
      T[w * 16 + q * 4 + reg][b * 16 + r16] = f2bf(acc[b][reg]);
  __syncthreads();
#pragma unroll
  for (int p = 0; p < 2; p++) {
    int idx = tid + p * 256;
    int fr = idx >> 3, ic8 = idx & 7;
    s16x8 v;
#pragma unroll
    for (int j = 0; j < 8; j++) v[j] = (short)T[ic8 * 8 + j][fr];
    *(s16x8*)(ht + (size_t)(f0 + fr) * NN + i0 + ic8 * 8) = v;
  }
}

// ---------------- 4. fused scores -> P(bf16) -> P @ h (MFMA), split-K ----------------
// i-tile 128: halves the dominant traffic term (ht logical re-reads 512->256 MB,
// re-read factor NN/ITILE 128->64). KSPLIT=8 keeps grid at 512 blocks (2/CU).
// Body structure identical to the proven R2/R8 schedule.
__global__ __launch_bounds__(256, 2) void k_att(const int* __restrict__ adj,
                                                const uint16_t* __restrict__ ht,
                                                const float* __restrict__ f1,
                                                const float* __restrict__ f2,
                                                float* __restrict__ l_arr,
                                                float* __restrict__ part) {
  __shared__ uint16_t Ps[128][72];   // 18 KB: 128 i x 64 j
  __shared__ uint16_t Hs[256][72];   // 36 KB: 256 f x 64 j
  int i0 = blockIdx.x * ITILE;
  int jbase = blockIdx.y * (NN / KSPLIT);   // 1024-wide K slice
  int tid = threadIdx.x;
  int w = tid >> 6, l = tid & 63;
  int q = l >> 4, r16 = l & 15;
  int prow = tid >> 1, pch = tid & 1;       // P: 2 threads/row, 32 j each
  int srow = tid >> 3, sch = tid & 7;       // Hs staging: 8 rows x 16B per thread
  float f1i = f1[i0 + prow];
  float lsum = 0.f;
  f32x4 acc[8][4];
#pragma unroll
  for (int a = 0; a < 8; a++)
#pragma unroll
    for (int b = 0; b < 4; b++) acc[a][b] = (f32x4)0.f;

  for (int s = 0; s < NN / KSPLIT; s += 64) {
    int j0 = jbase + s;
    // 1) issue Hs staging loads (held in regs; latency hidden by P-compute below)
    uint4 hv[8];
#pragma unroll
    for (int p = 0; p < 8; p++)
      hv[p] = *(const uint4*)(ht + (size_t)(p * 32 + srow) * NN + j0 + sch * 8);
    // 2) P tile 128x64 (32 entries per thread), coalesced adj int4 loads
    const int* ap = adj + (size_t)(i0 + prow) * NN + j0 + pch * 32;
    const float* fp = f2 + j0 + pch * 32;
    s16x8 pv[4];
#pragma unroll
    for (int g = 0; g < 4; ++g) {
      int4 Aa = *(const int4*)(ap + g * 8);
      int4 Ab = *(const int4*)(ap + g * 8 + 4);
      f32x4 Fa = *(const f32x4*)(fp + g * 8);
      f32x4 Fb = *(const f32x4*)(fp + g * 8 + 4);
#define PCOMP(Ac, Fc, kk) { float s_ = f1i + (Fc); float e_ = s_ > 0.f ? s_ : ALPHA * s_; \
                            float p_ = ((Ac) != 0) ? __expf(e_) : 1.0f; lsum += p_; \
                            pv[g][kk] = (short)f2bf(p_); }
      PCOMP(Aa.x, Fa[0], 0) PCOMP(Aa.y, Fa[1], 1) PCOMP(Aa.z, Fa[2], 2) PCOMP(Aa.w, Fa[3], 3)
      PCOMP(Ab.x, Fb[0], 4) PCOMP(Ab.y, Fb[1], 5) PCOMP(Ab.z, Fb[2], 6) PCOMP(Ab.w, Fb[3], 7)
#undef PCOMP
    }
    // 3) LDS writes
#pragma unroll
    for (int g = 0; g < 4; ++g)
      *(s16x8*)(&Ps[prow][pch * 32 + g * 8]) = pv[g];
#pragma unroll
    for (int p = 0; p < 8; p++)
      *(uint4*)(&Hs[p * 32 + srow][sch * 8]) = hv[p];
    __syncthreads();
    // 4) two K-chunks of MFMA per barrier pair (64 MFMA/wave/iter)
#pragma unroll
    for (int c = 0; c < 2; c++) {
      s16x8 Bf[4];
#pragma unroll
      for (int b = 0; b < 4; b++) Bf[b] = *(const s16x8*)(&Hs[w * 64 + b * 16 + r16][c * 32 + q * 8]);
#pragma unroll
      for (int a = 0; a < 8; a++) {
        s16x8 Af = *(const s16x8*)(&Ps[a * 16 + r16][c * 32 + q * 8]);
#pragma unroll
        for (int b = 0; b < 4; b++)
          acc[a][b] = __builtin_amdgcn_mfma_f32_16x16x32_bf16(Af, Bf[b], acc[a][b], 0, 0, 0);
      }
    }
    __syncthreads();
  }

  // reduce lsum over the 2 lanes sharing prow
  lsum += __shfl_down(lsum, 1);
  if (pch == 0) atomicAdd(&l_arr[i0 + prow], lsum);

  float* pb = part + (size_t)blockIdx.y * ((size_t)NN * FOUT);
#pragma unroll
  for (int a = 0; a < 8; a++)
#pragma unroll
    for (int b = 0; b < 4; b++)
#pragma unroll
      for (int reg = 0; reg < 4; reg++) {
        int row = i0 + a * 16 + q * 4 + reg;
        int col = w * 64 + b * 16 + r16;
        pb[(size_t)row * FOUT + col] = acc[a][b][reg];
      }
}

// ---------------- 5. combine split-K partials, /l, ELU, fp32 out ----------------
__global__ __launch_bounds__(256) void k_combine(const float* __restrict__ part,
                                                 const float* __restrict__ l_arr,
                                                 float* __restrict__ out) {
  int idx = (blockIdx.x * 256 + threadIdx.x) * 4;
  float r = 1.0f / l_arr[idx >> 8];
  f32x4 sum = (f32x4)0.f;
#pragma unroll
  for (int p = 0; p < KSPLIT; p++)
    sum += __builtin_nontemporal_load((const f32x4*)(part + (size_t)p * (NN * FOUT) + idx));
  f32x4 o;
#pragma unroll
  for (int i = 0; i < 4; i++) {
    float v = sum[i] * r;
    o[i] = v > 0.f ? v : (__expf(v) - 1.f);
  }
  __builtin_nontemporal_store(o, (f32x4*)(out + idx));
}

extern "C" void kernel_launch(void* const* d_in, const int* in_sizes, int n_in,
                              void* d_out, int out_size, void* d_ws, size_t ws_size,
                              hipStream_t stream) {
  const float* x   = (const float*)d_in[0];
  const int*   adj = (const int*)d_in[1];
  const float* W   = (const float*)d_in[2];
  const float* a   = (const float*)d_in[3];
  float* out = (float*)d_out;

  char* ws = (char*)d_ws;
  float*    wa1   = (float*)ws;                        // 512 f32
  float*    wa2   = wa1 + 512;                         // 512 f32
  float*    f1    = wa2 + 512;                         // 8192 f32
  float*    f2    = f1 + NN;                           // 8192 f32
  float*    l_arr = f2 + NN;                           // 8192 f32
  uint16_t* wt    = (uint16_t*)(l_arr + NN);           // 256*512 bf16 (256 KB)
  uint16_t* xb    = wt + (size_t)FOUT * FIN;           // 8192*512 bf16 (8 MB)
  uint16_t* ht    = xb + (size_t)NN * FIN;             // 256*8192 bf16 (4 MB)
  float*    part  = (float*)(ht + (size_t)NN * FOUT);  // KSPLIT * 8192*256 f32 (64 MB)

  k_wa_prep<<<130, 256, 0, stream>>>(W, a, wt, wa1, wa2);
  k_f1f2<<<NN / 4, 256, 0, stream>>>(x, wa1, wa2, f1, f2, xb, l_arr);
  k_gemm_ht<<<dim3(NN / 64, FOUT / 64), 256, 0, stream>>>(xb, wt, ht);
  k_att<<<dim3(NN / ITILE, KSPLIT), 256, 0, stream>>>(adj, ht, f1, f2, l_arr, part);
  k_combine<<<NN * FOUT / 1024, 256, 0, stream>>>(part, l_arr, out);
}

// Round 10
// 442.535 us; speedup vs baseline: 1.0668x; 1.0668x over previous
//
#include <hip/hip_runtime.h>
#include <stdint.h>

#define NN 8192
#define FIN 512
#define FOUT 256
#define ALPHA 0.2f
#define KSPLIT 4

typedef float f32x4 __attribute__((ext_vector_type(4)));
typedef short s16x8 __attribute__((ext_vector_type(8)));

__device__ __forceinline__ uint16_t f2bf(float f) {
  union { float f; uint32_t u; } v; v.f = f;
  uint32_t u = v.u + 0x7fffu + ((v.u >> 16) & 1u);
  return (uint16_t)(u >> 16);
}

// ---------------- 1. merged: wt[f][k] = bf16(W[k][f])  +  wa1/wa2 = W @ a1/a2 ----------------
__global__ __launch_bounds__(256) void k_wa_prep(const float* __restrict__ W,
                                                 const float* __restrict__ a,
                                                 uint16_t* __restrict__ wt,
                                                 float* __restrict__ wa1, float* __restrict__ wa2) {
  int bx = blockIdx.x;
  int tid = threadIdx.x;
  if (bx < 128) {
    int idx = bx * 256 + tid;
    int f  = idx >> 7;
    int k4 = (idx & 127) * 4;
    ushort4 o;
    o.x = f2bf(W[(size_t)(k4 + 0) * FOUT + f]);
    o.y = f2bf(W[(size_t)(k4 + 1) * FOUT + f]);
    o.z = f2bf(W[(size_t)(k4 + 2) * FOUT + f]);
    o.w = f2bf(W[(size_t)(k4 + 3) * FOUT + f]);
    *(ushort4*)(wt + (size_t)f * FIN + k4) = o;
  } else {
    __shared__ float a1[256], a2[256];
    a1[tid] = a[tid];
    a2[tid] = a[tid + 256];
    __syncthreads();
    int m = (bx - 128) * 256 + tid;   // 0..511
    const float* wrow = W + (size_t)m * FOUT;
    float s1 = 0.f, s2 = 0.f;
    for (int k = 0; k < FOUT; k += 4) {
      f32x4 v = *(const f32x4*)(wrow + k);
#pragma unroll
      for (int i = 0; i < 4; i++) {
        s1 += v[i] * a1[k + i];
        s2 += v[i] * a2[k + i];
      }
    }
    wa1[m] = s1; wa2[m] = s2;
  }
}

// ---------------- 2. f1/f2 = x @ wa1/wa2 + x->bf16 + l_arr zero ----------------
__global__ __launch_bounds__(256) void k_f1f2(const float* __restrict__ x,
                                              const float* __restrict__ wa1,
                                              const float* __restrict__ wa2,
                                              float* __restrict__ f1, float* __restrict__ f2,
                                              uint16_t* __restrict__ xb,
                                              float* __restrict__ l_arr) {
  __shared__ float s1[512], s2[512];
  int tid = threadIdx.x;
  if (tid < 4) l_arr[blockIdx.x * 4 + tid] = 0.f;
  s1[tid] = wa1[tid]; s1[tid + 256] = wa1[tid + 256];
  s2[tid] = wa2[tid]; s2[tid + 256] = wa2[tid + 256];
  __syncthreads();
  int w = tid >> 6, l = tid & 63;
  int row = blockIdx.x * 4 + w;
  const float* xr = x + (size_t)row * FIN + l * 8;
  f32x4 v0 = *(const f32x4*)xr;
  f32x4 v1 = *(const f32x4*)(xr + 4);
  uint4 pk;
  pk.x = (uint32_t)f2bf(v0[0]) | ((uint32_t)f2bf(v0[1]) << 16);
  pk.y = (uint32_t)f2bf(v0[2]) | ((uint32_t)f2bf(v0[3]) << 16);
  pk.z = (uint32_t)f2bf(v1[0]) | ((uint32_t)f2bf(v1[1]) << 16);
  pk.w = (uint32_t)f2bf(v1[2]) | ((uint32_t)f2bf(v1[3]) << 16);
  *(uint4*)(xb + (size_t)row * FIN + l * 8) = pk;
  int kb = l * 8;
  float d1 = 0.f, d2 = 0.f;
#pragma unroll
  for (int i = 0; i < 4; i++) {
    d1 += v0[i] * s1[kb + i] + v1[i] * s1[kb + 4 + i];
    d2 += v0[i] * s2[kb + i] + v1[i] * s2[kb + 4 + i];
  }
#pragma unroll
  for (int off = 32; off; off >>= 1) {
    d1 += __shfl_down(d1, off);
    d2 += __shfl_down(d2, off);
  }
  if (l == 0) { f1[row] = d1; f2[row] = d2; }
}

// ---------------- 3. ht[f][i] = (xb @ W)^T  -- gemm + LDS-transpose epilogue ----------------
// BK=128: 4 K-steps (was 8) -> half the barrier/wait events. LDS 44 KB, 2 blocks/CU.
__global__ __launch_bounds__(256, 2) void k_gemm_ht(const uint16_t* __restrict__ xb,
                                                    const uint16_t* __restrict__ wt,
                                                    uint16_t* __restrict__ ht) {
  __shared__ uint16_t Xs[64][136];
  __shared__ uint16_t Ws[64][136];
  __shared__ uint16_t T[64][72];
  int i0 = blockIdx.x * 64;
  int f0 = blockIdx.y * 64;
  int tid = threadIdx.x;
  int w = tid >> 6, l = tid & 63;
  int q = l >> 4, r16 = l & 15;
  f32x4 acc[4];
#pragma unroll
  for (int b = 0; b < 4; b++) acc[b] = (f32x4)0.f;

  int srow = tid >> 2, sch = tid & 3;
  for (int k0 = 0; k0 < FIN; k0 += 128) {
    const uint16_t* xp = xb + (size_t)(i0 + srow) * FIN + k0;
    const uint16_t* wp = wt + (size_t)(f0 + srow) * FIN + k0;
#pragma unroll
    for (int c = 0; c < 4; c++) {
      uint4 xv = *(const uint4*)(xp + c * 32 + sch * 8);
      uint4 wv = *(const uint4*)(wp + c * 32 + sch * 8);
      *(uint4*)(&Xs[srow][c * 32 + sch * 8]) = xv;
      *(uint4*)(&Ws[srow][c * 32 + sch * 8]) = wv;
    }
    __syncthreads();
#pragma unroll
    for (int c = 0; c < 4; c++) {
      s16x8 A = *(const s16x8*)(&Xs[w * 16 + r16][c * 32 + q * 8]);
      s16x8 B[4];
#pragma unroll
      for (int b = 0; b < 4; b++) B[b] = *(const s16x8*)(&Ws[b * 16 + r16][c * 32 + q * 8]);
#pragma unroll
      for (int b = 0; b < 4; b++)
        acc[b] = __builtin_amdgcn_mfma_f32_16x16x32_bf16(A, B[b], acc[b], 0, 0, 0);
    }
    __syncthreads();
  }
#pragma unroll
  for (int b = 0; b < 4; b++)
#pragma unroll
    for (int reg = 0; reg < 4; reg++)
      T[w * 16 + q * 4 + reg][b * 16 + r16] = f2bf(acc[b][reg]);
  __syncthreads();
#pragma unroll
  for (int p = 0; p < 2; p++) {
    int idx = tid + p * 256;
    int fr = idx >> 3, ic8 = idx & 7;
    s16x8 v;
#pragma unroll
    for (int j = 0; j < 8; j++) v[j] = (short)T[ic8 * 8 + j][fr];
    *(s16x8*)(ht + (size_t)(f0 + fr) * NN + i0 + ic8 * 8) = v;
  }
}

// ---------------- 4. fused scores -> P(bf16) -> P @ h (MFMA), split-K ----------------
// R8 champion body + adj/f2 batched ONE HALF-ITERATION AHEAD (double register set,
// loop unrolled x2). Each P-compute consumes loads issued a full phase earlier, so
// the exposed ~HBM-latency wait per iteration collapses to the barrier-drain residue.
__global__ __launch_bounds__(256, 2) void k_att(const int* __restrict__ adj,
                                                const uint16_t* __restrict__ ht,
                                                const float* __restrict__ f1,
                                                const float* __restrict__ f2,
                                                float* __restrict__ l_arr,
                                                float* __restrict__ part) {
  __shared__ uint16_t Ps[64][72];    // 64 rows i x 64 j
  __shared__ uint16_t Hs[256][72];   // 256 f x 64 j
  int i0 = blockIdx.x * 64;
  int jbase = blockIdx.y * (NN / KSPLIT);   // 2048-wide K slice
  int tid = threadIdx.x;
  int w = tid >> 6, l = tid & 63;
  int q = l >> 4, r16 = l & 15;
  int prow = tid >> 2, pch = tid & 3;       // P: 16 j-elems per thread
  int srow = tid >> 3, sch = tid & 7;       // Hs staging: 8 rows x 16B per thread
  float f1i = f1[i0 + prow];
  float lsum = 0.f;
  f32x4 acc[4][4];
#pragma unroll
  for (int a = 0; a < 4; a++)
#pragma unroll
    for (int b = 0; b < 4; b++) acc[a][b] = (f32x4)0.f;

  const int*   arow = adj + (size_t)(i0 + prow) * NN + jbase + pch * 16;
  const float* frow = f2 + jbase + pch * 16;

#define LOADAF(AV, FV, J) { \
    const int* ap_ = arow + (J); \
    AV[0] = *(const int4*)ap_;        AV[1] = *(const int4*)(ap_ + 4); \
    AV[2] = *(const int4*)(ap_ + 8);  AV[3] = *(const int4*)(ap_ + 12); \
    const float* fp_ = frow + (J); \
    FV[0] = *(const f32x4*)fp_;       FV[1] = *(const f32x4*)(fp_ + 4); \
    FV[2] = *(const f32x4*)(fp_ + 8); FV[3] = *(const f32x4*)(fp_ + 12); }

#define PCOMP(dst, Ac, Fc, kk) { float s_ = f1i + (Fc); float e_ = s_ > 0.f ? s_ : ALPHA * s_; \
                                 float p_ = ((Ac) != 0) ? __expf(e_) : 1.0f; lsum += p_; \
                                 dst[kk] = (short)f2bf(p_); }

#define HALF(J, AV, FV, DOPRE, PJ, BV, GV) { \
    int j0_ = jbase + (J); \
    uint4 hv[8]; \
    _Pragma("unroll") for (int p = 0; p < 8; p++) \
      hv[p] = *(const uint4*)(ht + (size_t)(p * 32 + srow) * NN + j0_ + sch * 8); \
    if (DOPRE) LOADAF(BV, GV, PJ); \
    s16x8 pv0, pv1; \
    PCOMP(pv0, AV[0].x, FV[0][0], 0) PCOMP(pv0, AV[0].y, FV[0][1], 1) \
    PCOMP(pv0, AV[0].z, FV[0][2], 2) PCOMP(pv0, AV[0].w, FV[0][3], 3) \
    PCOMP(pv0, AV[1].x, FV[1][0], 4) PCOMP(pv0, AV[1].y, FV[1][1], 5) \
    PCOMP(pv0, AV[1].z, FV[1][2], 6) PCOMP(pv0, AV[1].w, FV[1][3], 7) \
    PCOMP(pv1, AV[2].x, FV[2][0], 0) PCOMP(pv1, AV[2].y, FV[2][1], 1) \
    PCOMP(pv1, AV[2].z, FV[2][2], 2) PCOMP(pv1, AV[2].w, FV[2][3], 3) \
    PCOMP(pv1, AV[3].x, FV[3][0], 4) PCOMP(pv1, AV[3].y, FV[3][1], 5) \
    PCOMP(pv1, AV[3].z, FV[3][2], 6) PCOMP(pv1, AV[3].w, FV[3][3], 7) \
    *(s16x8*)(&Ps[prow][pch * 16]) = pv0; \
    *(s16x8*)(&Ps[prow][pch * 16 + 8]) = pv1; \
    _Pragma("unroll") for (int p = 0; p < 8; p++) \
      *(uint4*)(&Hs[p * 32 + srow][sch * 8]) = hv[p]; \
    __syncthreads(); \
    _Pragma("unroll") for (int c = 0; c < 2; c++) { \
      s16x8 Af[4], Bf[4]; \
      _Pragma("unroll") for (int a = 0; a < 4; a++) \
        Af[a] = *(const s16x8*)(&Ps[a * 16 + r16][c * 32 + q * 8]); \
      _Pragma("unroll") for (int b = 0; b < 4; b++) \
        Bf[b] = *(const s16x8*)(&Hs[w * 64 + b * 16 + r16][c * 32 + q * 8]); \
      _Pragma("unroll") for (int a = 0; a < 4; a++) \
        _Pragma("unroll") for (int b = 0; b < 4; b++) \
          acc[a][b] = __builtin_amdgcn_mfma_f32_16x16x32_bf16(Af[a], Bf[b], acc[a][b], 0, 0, 0); \
    } \
    __syncthreads(); }

  int4  Aa[4], Ab[4];
  f32x4 Fa[4], Fb[4];
  LOADAF(Aa, Fa, 0);
  const int NSLICE = NN / KSPLIT;   // 2048 -> 32 half-iterations of 64
  for (int s = 0; s < NSLICE / 64; s += 2) {
    HALF(s * 64,       Aa, Fa, true,                       (s + 1) * 64,                       Ab, Fb);
    HALF((s + 1) * 64, Ab, Fb, (s + 2) * 64 < NSLICE,      ((s + 2) * 64 < NSLICE) ? (s + 2) * 64 : 0, Aa, Fa);
  }
#undef HALF
#undef PCOMP
#undef LOADAF

  // reduce lsum over the 4 lanes sharing prow (lanes pch=0..3 are consecutive)
  lsum += __shfl_down(lsum, 2);
  lsum += __shfl_down(lsum, 1);
  if (pch == 0) atomicAdd(&l_arr[i0 + prow], lsum);

  float* pb = part + (size_t)blockIdx.y * ((size_t)NN * FOUT);
#pragma unroll
  for (int a = 0; a < 4; a++)
#pragma unroll
    for (int b = 0; b < 4; b++)
#pragma unroll
      for (int reg = 0; reg < 4; reg++) {
        int row = i0 + a * 16 + q * 4 + reg;
        int col = w * 64 + b * 16 + r16;
        pb[(size_t)row * FOUT + col] = acc[a][b][reg];
      }
}

// ---------------- 5. combine split-K partials, /l, ELU, fp32 out ----------------
__global__ __launch_bounds__(256) void k_combine(const float* __restrict__ part,
                                                 const float* __restrict__ l_arr,
                                                 float* __restrict__ out) {
  int idx = (blockIdx.x * 256 + threadIdx.x) * 4;
  float r = 1.0f / l_arr[idx >> 8];
  f32x4 v0 = __builtin_nontemporal_load((const f32x4*)(part + 0 * (size_t)(NN * FOUT) + idx));
  f32x4 v1 = __builtin_nontemporal_load((const f32x4*)(part + 1 * (size_t)(NN * FOUT) + idx));
  f32x4 v2 = __builtin_nontemporal_load((const f32x4*)(part + 2 * (size_t)(NN * FOUT) + idx));
  f32x4 v3 = __builtin_nontemporal_load((const f32x4*)(part + 3 * (size_t)(NN * FOUT) + idx));
  f32x4 o;
#pragma unroll
  for (int i = 0; i < 4; i++) {
    float v = (v0[i] + v1[i] + v2[i] + v3[i]) * r;
    o[i] = v > 0.f ? v : (__expf(v) - 1.f);
  }
  __builtin_nontemporal_store(o, (f32x4*)(out + idx));
}

extern "C" void kernel_launch(void* const* d_in, const int* in_sizes, int n_in,
                              void* d_out, int out_size, void* d_ws, size_t ws_size,
                              hipStream_t stream) {
  const float* x   = (const float*)d_in[0];
  const int*   adj = (const int*)d_in[1];
  const float* W   = (const float*)d_in[2];
  const float* a   = (const float*)d_in[3];
  float* out = (float*)d_out;

  char* ws = (char*)d_ws;
  float*    wa1   = (float*)ws;                        // 512 f32
  float*    wa2   = wa1 + 512;                         // 512 f32
  float*    f1    = wa2 + 512;                         // 8192 f32
  float*    f2    = f1 + NN;                           // 8192 f32
  float*    l_arr = f2 + NN;                           // 8192 f32
  uint16_t* wt    = (uint16_t*)(l_arr + NN);           // 256*512 bf16 (256 KB)
  uint16_t* xb    = wt + (size_t)FOUT * FIN;           // 8192*512 bf16 (8 MB)
  uint16_t* ht    = xb + (size_t)NN * FIN;             // 256*8192 bf16 (4 MB)
  float*    part  = (float*)(ht + (size_t)NN * FOUT);  // KSPLIT * 8192*256 f32 (32 MB)

  k_wa_prep<<<130, 256, 0, stream>>>(W, a, wt, wa1, wa2);
  k_f1f2<<<NN / 4, 256, 0, stream>>>(x, wa1, wa2, f1, f2, xb, l_arr);
  k_gemm_ht<<<dim3(NN / 64, FOUT / 64), 256, 0, stream>>>(xb, wt, ht);
  k_att<<<dim3(NN / 64, KSPLIT), 256, 0, stream>>>(adj, ht, f1, f2, l_arr, part);
  k_combine<<<NN * FOUT / 1024, 256, 0, stream>>>(part, l_arr, out);
}

// Round 11
// 435.291 us; speedup vs baseline: 1.0846x; 1.0166x over previous
//
#include <hip/hip_runtime.h>
#include <stdint.h>

#define NN 8192
#define FIN 512
#define FOUT 256
#define ALPHA 0.2f
#define KSPLIT 4

typedef float f32x4 __attribute__((ext_vector_type(4)));
typedef short s16x8 __attribute__((ext_vector_type(8)));

__device__ __forceinline__ uint16_t f2bf(float f) {
  union { float f; uint32_t u; } v; v.f = f;
  uint32_t u = v.u + 0x7fffu + ((v.u >> 16) & 1u);
  return (uint16_t)(u >> 16);
}

// one-instruction RNE pack of two f32 -> bf16x2 (no builtin on gfx950; inline asm)
__device__ __forceinline__ uint32_t cvtpk(float lo, float hi) {
  uint32_t r;
  asm("v_cvt_pk_bf16_f32 %0, %1, %2" : "=v"(r) : "v"(lo), "v"(hi));
  return r;
}

// ---------------- 1. merged: wt[f][k] = bf16(W[k][f])  +  wa1/wa2 = W @ a1/a2 ----------------
__global__ __launch_bounds__(256) void k_wa_prep(const float* __restrict__ W,
                                                 const float* __restrict__ a,
                                                 uint16_t* __restrict__ wt,
                                                 float* __restrict__ wa1, float* __restrict__ wa2) {
  int bx = blockIdx.x;
  int tid = threadIdx.x;
  if (bx < 128) {
    int idx = bx * 256 + tid;
    int f  = idx >> 7;
    int k4 = (idx & 127) * 4;
    ushort4 o;
    o.x = f2bf(W[(size_t)(k4 + 0) * FOUT + f]);
    o.y = f2bf(W[(size_t)(k4 + 1) * FOUT + f]);
    o.z = f2bf(W[(size_t)(k4 + 2) * FOUT + f]);
    o.w = f2bf(W[(size_t)(k4 + 3) * FOUT + f]);
    *(ushort4*)(wt + (size_t)f * FIN + k4) = o;
  } else {
    __shared__ float a1[256], a2[256];
    a1[tid] = a[tid];
    a2[tid] = a[tid + 256];
    __syncthreads();
    int m = (bx - 128) * 256 + tid;   // 0..511
    const float* wrow = W + (size_t)m * FOUT;
    float s1 = 0.f, s2 = 0.f;
    for (int k = 0; k < FOUT; k += 4) {
      f32x4 v = *(const f32x4*)(wrow + k);
#pragma unroll
      for (int i = 0; i < 4; i++) {
        s1 += v[i] * a1[k + i];
        s2 += v[i] * a2[k + i];
      }
    }
    wa1[m] = s1; wa2[m] = s2;
  }
}

// ---------------- 2. f1/f2 = x @ wa1/wa2 + x->bf16 + l_arr zero ----------------
__global__ __launch_bounds__(256) void k_f1f2(const float* __restrict__ x,
                                              const float* __restrict__ wa1,
                                              const float* __restrict__ wa2,
                                              float* __restrict__ f1, float* __restrict__ f2,
                                              uint16_t* __restrict__ xb,
                                              float* __restrict__ l_arr) {
  __shared__ float s1[512], s2[512];
  int tid = threadIdx.x;
  if (tid < 4) l_arr[blockIdx.x * 4 + tid] = 0.f;
  s1[tid] = wa1[tid]; s1[tid + 256] = wa1[tid + 256];
  s2[tid] = wa2[tid]; s2[tid + 256] = wa2[tid + 256];
  __syncthreads();
  int w = tid >> 6, l = tid & 63;
  int row = blockIdx.x * 4 + w;
  const float* xr = x + (size_t)row * FIN + l * 8;
  f32x4 v0 = *(const f32x4*)xr;
  f32x4 v1 = *(const f32x4*)(xr + 4);
  uint4 pk;
  pk.x = cvtpk(v0[0], v0[1]);
  pk.y = cvtpk(v0[2], v0[3]);
  pk.z = cvtpk(v1[0], v1[1]);
  pk.w = cvtpk(v1[2], v1[3]);
  *(uint4*)(xb + (size_t)row * FIN + l * 8) = pk;
  int kb = l * 8;
  float d1 = 0.f, d2 = 0.f;
#pragma unroll
  for (int i = 0; i < 4; i++) {
    d1 += v0[i] * s1[kb + i] + v1[i] * s1[kb + 4 + i];
    d2 += v0[i] * s2[kb + i] + v1[i] * s2[kb + 4 + i];
  }
#pragma unroll
  for (int off = 32; off; off >>= 1) {
    d1 += __shfl_down(d1, off);
    d2 += __shfl_down(d2, off);
  }
  if (l == 0) { f1[row] = d1; f2[row] = d2; }
}

// ---------------- 3. ht[f][i] = (xb @ W)^T  -- gemm + LDS-transpose epilogue ----------------
// R8 champion form: BK=64.
__global__ __launch_bounds__(256, 2) void k_gemm_ht(const uint16_t* __restrict__ xb,
                                                    const uint16_t* __restrict__ wt,
                                                    uint16_t* __restrict__ ht) {
  __shared__ uint16_t Xs[64][72];
  __shared__ uint16_t Ws[64][72];
  __shared__ uint16_t T[64][72];
  int i0 = blockIdx.x * 64;
  int f0 = blockIdx.y * 64;
  int tid = threadIdx.x;
  int w = tid >> 6, l = tid & 63;
  int q = l >> 4, r16 = l & 15;
  f32x4 acc[4];
#pragma unroll
  for (int b = 0; b < 4; b++) acc[b] = (f32x4)0.f;

  int srow = tid >> 2, sch = tid & 3;
  for (int k0 = 0; k0 < FIN; k0 += 64) {
    const uint16_t* xp = xb + (size_t)(i0 + srow) * FIN + k0;
    const uint16_t* wp = wt + (size_t)(f0 + srow) * FIN + k0;
    uint4 xv0 = *(const uint4*)(xp + sch * 8);
    uint4 xv1 = *(const uint4*)(xp + 32 + sch * 8);
    uint4 wv0 = *(const uint4*)(wp + sch * 8);
    uint4 wv1 = *(const uint4*)(wp + 32 + sch * 8);
    *(uint4*)(&Xs[srow][sch * 8]) = xv0;
    *(uint4*)(&Xs[srow][32 + sch * 8]) = xv1;
    *(uint4*)(&Ws[srow][sch * 8]) = wv0;
    *(uint4*)(&Ws[srow][32 + sch * 8]) = wv1;
    __syncthreads();
#pragma unroll
    for (int c = 0; c < 2; c++) {
      s16x8 A = *(const s16x8*)(&Xs[w * 16 + r16][c * 32 + q * 8]);
      s16x8 B[4];
#pragma unroll
      for (int b = 0; b < 4; b++) B[b] = *(const s16x8*)(&Ws[b * 16 + r16][c * 32 + q * 8]);
#pragma unroll
      for (int b = 0; b < 4; b++)
        acc[b] = __builtin_amdgcn_mfma_f32_16x16x32_bf16(A, B[b], acc[b], 0, 0, 0);
    }
    __syncthreads();
  }
#pragma unroll
  for (int b = 0; b < 4; b++)
#pragma unroll
    for (int reg = 0; reg < 4; reg++)
      T[w * 16 + q * 4 + reg][b * 16 + r16] = f2bf(acc[b][reg]);
  __syncthreads();
#pragma unroll
  for (int p = 0; p < 2; p++) {
    int idx = tid + p * 256;
    int fr = idx >> 3, ic8 = idx & 7;
    s16x8 v;
#pragma unroll
    for (int j = 0; j < 8; j++) v[j] = (short)T[ic8 * 8 + j][fr];
    *(s16x8*)(ht + (size_t)(f0 + fr) * NN + i0 + ic8 * 8) = v;
  }
}

// ---------------- 4. fused scores -> P(bf16) -> P @ h (MFMA), split-K ----------------
// R8 champion body; only change: 16x f2bf + 8x or-pack replaced by 8x
// v_cvt_pk_bf16_f32 (one-instruction RNE pair convert+pack; bit-identical output).
__global__ __launch_bounds__(256, 2) void k_att(const int* __restrict__ adj,
                                                const uint16_t* __restrict__ ht,
                                                const float* __restrict__ f1,
                                                const float* __restrict__ f2,
                                                float* __restrict__ l_arr,
                                                float* __restrict__ part) {
  __shared__ uint16_t Ps[64][72];    // 64 rows i x 64 j
  __shared__ uint16_t Hs[256][72];   // 256 f x 64 j
  int i0 = blockIdx.x * 64;
  int jbase = blockIdx.y * (NN / KSPLIT);   // 2048-wide K slice
  int tid = threadIdx.x;
  int w = tid >> 6, l = tid & 63;
  int q = l >> 4, r16 = l & 15;
  int prow = tid >> 2, pch = tid & 3;       // P: 16 j-elems per thread
  int srow = tid >> 3, sch = tid & 7;       // Hs staging: 8 rows x 16B per thread
  float f1i = f1[i0 + prow];
  float lsum = 0.f;
  f32x4 acc[4][4];
#pragma unroll
  for (int a = 0; a < 4; a++)
#pragma unroll
    for (int b = 0; b < 4; b++) acc[a][b] = (f32x4)0.f;

  for (int s = 0; s < NN / KSPLIT; s += 64) {
    int j0 = jbase + s;
    // 1) issue Hs staging loads (held in regs; latency hidden by P-compute below)
    uint4 hv[8];
#pragma unroll
    for (int p = 0; p < 8; p++)
      hv[p] = *(const uint4*)(ht + (size_t)(p * 32 + srow) * NN + j0 + sch * 8);
    // 2) P tile 64x64 (16 entries per thread), coalesced adj int4 loads
    const int* ap = adj + (size_t)(i0 + prow) * NN + j0 + pch * 16;
    int4 A0 = *(const int4*)ap;
    int4 A1 = *(const int4*)(ap + 4);
    int4 A2 = *(const int4*)(ap + 8);
    int4 A3 = *(const int4*)(ap + 12);
    f32x4 F0 = *(const f32x4*)(f2 + j0 + pch * 16);
    f32x4 F1 = *(const f32x4*)(f2 + j0 + pch * 16 + 4);
    f32x4 F2 = *(const f32x4*)(f2 + j0 + pch * 16 + 8);
    f32x4 F3 = *(const f32x4*)(f2 + j0 + pch * 16 + 12);
    float P0[8], P1[8];
#define PCOMP(arr, Ac, Fc, kk) { float s_ = f1i + (Fc); float e_ = s_ > 0.f ? s_ : ALPHA * s_; \
                                 float p_ = ((Ac) != 0) ? __expf(e_) : 1.0f; lsum += p_; \
                                 arr[kk] = p_; }
    PCOMP(P0, A0.x, F0[0], 0); PCOMP(P0, A0.y, F0[1], 1);
    PCOMP(P0, A0.z, F0[2], 2); PCOMP(P0, A0.w, F0[3], 3);
    PCOMP(P0, A1.x, F1[0], 4); PCOMP(P0, A1.y, F1[1], 5);
    PCOMP(P0, A1.z, F1[2], 6); PCOMP(P0, A1.w, F1[3], 7);
    PCOMP(P1, A2.x, F2[0], 0); PCOMP(P1, A2.y, F2[1], 1);
    PCOMP(P1, A2.z, F2[2], 2); PCOMP(P1, A2.w, F2[3], 3);
    PCOMP(P1, A3.x, F3[0], 4); PCOMP(P1, A3.y, F3[1], 5);
    PCOMP(P1, A3.z, F3[2], 6); PCOMP(P1, A3.w, F3[3], 7);
#undef PCOMP
    // 3) LDS writes (cvt_pk: entry 2g -> lo16, 2g+1 -> hi16; little-endian matches layout)
    uint4 u0, u1;
    u0.x = cvtpk(P0[0], P0[1]); u0.y = cvtpk(P0[2], P0[3]);
    u0.z = cvtpk(P0[4], P0[5]); u0.w = cvtpk(P0[6], P0[7]);
    u1.x = cvtpk(P1[0], P1[1]); u1.y = cvtpk(P1[2], P1[3]);
    u1.z = cvtpk(P1[4], P1[5]); u1.w = cvtpk(P1[6], P1[7]);
    *(uint4*)(&Ps[prow][pch * 16]) = u0;
    *(uint4*)(&Ps[prow][pch * 16 + 8]) = u1;
#pragma unroll
    for (int p = 0; p < 8; p++)
      *(uint4*)(&Hs[p * 32 + srow][sch * 8]) = hv[p];
    __syncthreads();
    // 4) two K-chunks of MFMA per barrier pair
#pragma unroll
    for (int c = 0; c < 2; c++) {
      s16x8 Af[4], Bf[4];
#pragma unroll
      for (int a = 0; a < 4; a++) Af[a] = *(const s16x8*)(&Ps[a * 16 + r16][c * 32 + q * 8]);
#pragma unroll
      for (int b = 0; b < 4; b++) Bf[b] = *(const s16x8*)(&Hs[w * 64 + b * 16 + r16][c * 32 + q * 8]);
#pragma unroll
      for (int a = 0; a < 4; a++)
#pragma unroll
        for (int b = 0; b < 4; b++)
          acc[a][b] = __builtin_amdgcn_mfma_f32_16x16x32_bf16(Af[a], Bf[b], acc[a][b], 0, 0, 0);
    }
    __syncthreads();
  }

  // reduce lsum over the 4 lanes sharing prow (lanes pch=0..3 are consecutive)
  lsum += __shfl_down(lsum, 2);
  lsum += __shfl_down(lsum, 1);
  if (pch == 0) atomicAdd(&l_arr[i0 + prow], lsum);

  float* pb = part + (size_t)blockIdx.y * ((size_t)NN * FOUT);
#pragma unroll
  for (int a = 0; a < 4; a++)
#pragma unroll
    for (int b = 0; b < 4; b++)
#pragma unroll
      for (int reg = 0; reg < 4; reg++) {
        int row = i0 + a * 16 + q * 4 + reg;
        int col = w * 64 + b * 16 + r16;
        pb[(size_t)row * FOUT + col] = acc[a][b][reg];
      }
}

// ---------------- 5. combine split-K partials, /l, ELU, fp32 out ----------------
__global__ __launch_bounds__(256) void k_combine(const float* __restrict__ part,
                                                 const float* __restrict__ l_arr,
                                                 float* __restrict__ out) {
  int idx = (blockIdx.x * 256 + threadIdx.x) * 4;
  float r = 1.0f / l_arr[idx >> 8];
  f32x4 v0 = __builtin_nontemporal_load((const f32x4*)(part + 0 * (size_t)(NN * FOUT) + idx));
  f32x4 v1 = __builtin_nontemporal_load((const f32x4*)(part + 1 * (size_t)(NN * FOUT) + idx));
  f32x4 v2 = __builtin_nontemporal_load((const f32x4*)(part + 2 * (size_t)(NN * FOUT) + idx));
  f32x4 v3 = __builtin_nontemporal_load((const f32x4*)(part + 3 * (size_t)(NN * FOUT) + idx));
  f32x4 o;
#pragma unroll
  for (int i = 0; i < 4; i++) {
    float v = (v0[i] + v1[i] + v2[i] + v3[i]) * r;
    o[i] = v > 0.f ? v : (__expf(v) - 1.f);
  }
  __builtin_nontemporal_store(o, (f32x4*)(out + idx));
}

extern "C" void kernel_launch(void* const* d_in, const int* in_sizes, int n_in,
                              void* d_out, int out_size, void* d_ws, size_t ws_size,
                              hipStream_t stream) {
  const float* x   = (const float*)d_in[0];
  const int*   adj = (const int*)d_in[1];
  const float* W   = (const float*)d_in[2];
  const float* a   = (const float*)d_in[3];
  float* out = (float*)d_out;

  char* ws = (char*)d_ws;
  float*    wa1   = (float*)ws;                        // 512 f32
  float*    wa2   = wa1 + 512;                         // 512 f32
  float*    f1    = wa2 + 512;                         // 8192 f32
  float*    f2    = f1 + NN;                           // 8192 f32
  float*    l_arr = f2 + NN;                           // 8192 f32
  uint16_t* wt    = (uint16_t*)(l_arr + NN);           // 256*512 bf16 (256 KB)
  uint16_t* xb    = wt + (size_t)FOUT * FIN;           // 8192*512 bf16 (8 MB)
  uint16_t* ht    = xb + (size_t)NN * FIN;             // 256*8192 bf16 (4 MB)
  float*    part  = (float*)(ht + (size_t)NN * FOUT);  // KSPLIT * 8192*256 f32 (32 MB)

  k_wa_prep<<<130, 256, 0, stream>>>(W, a, wt, wa1, wa2);
  k_f1f2<<<NN / 4, 256, 0, stream>>>(x, wa1, wa2, f1, f2, xb, l_arr);
  k_gemm_ht<<<dim3(NN / 64, FOUT / 64), 256, 0, stream>>>(xb, wt, ht);
  k_att<<<dim3(NN / 64, KSPLIT), 256, 0, stream>>>(adj, ht, f1, f2, l_arr, part);
  k_combine<<<NN * FOUT / 1024, 256, 0, stream>>>(part, l_arr, out);
}